// Round 1
// baseline (94.040 us; speedup 1.0000x reference)
//
#include <hip/hip_runtime.h>

// ConvNearestNeighbor forward, MI355X.
// x: (B=16, C=32, H=32, W=32) f32; neighbors: (NUM=32, C=32, 9) f32
// out: (B, NUM*C, H, W) f32
// out[b, n*C+c... wait: reshape(B, num*C, H, W) of (B, num, C, H, W) ->
//   out[((b*NUM + n)*C + c)*H*W + h*W + w]
//     = max_k | x[b,c,h-row_k,w-col_k] (zero-pad) - neighbors[n,c,k] |
//   k = 3*(row+1) + (col+1), row,col in {-1,0,1}

#define BB 16
#define CC 32
#define HH 32
#define WW 32
#define NUMN 32

__global__ __launch_bounds__(256) void conv_nn_kernel(
    const float* __restrict__ x,
    const float* __restrict__ neighbors,
    float* __restrict__ out)
{
    // padded x plane (halo of 1), +2 col pad for LDS bank spread
    __shared__ float tile[HH + 2][WW + 4];
    __shared__ float nlds[NUMN * 9];

    const int bc = blockIdx.x;        // 0 .. B*C-1
    const int b  = bc >> 5;           // / C
    const int c  = bc & 31;           // % C
    const int t  = threadIdx.x;       // 0..255

    // ---- stage x plane with zero halo ----
    const float* xplane = x + (b * CC + c) * (HH * WW);
    for (int idx = t; idx < 34 * 34; idx += 256) {
        int row = idx / 34;           // 0..33
        int col = idx - row * 34;     // 0..33
        int h = row - 1, w = col - 1;
        float v = 0.0f;
        if ((unsigned)h < (unsigned)HH && (unsigned)w < (unsigned)WW)
            v = xplane[h * WW + w];
        tile[row][col] = v;
    }
    // ---- stage neighbors[:, c, :] : NUM*9 floats ----
    for (int i = t; i < NUMN * 9; i += 256) {
        int n = i / 9;
        int k = i - n * 9;
        nlds[i] = neighbors[(n * CC + c) * 9 + k];
    }
    __syncthreads();

    // thread -> (h, w0..w0+3); plane-linear offset = h*W + w0 = 4*t
    const int h  = t >> 3;
    const int w0 = (t & 7) * 4;

    // 3 rows x 6 cols register window of the padded tile
    float xr[3][6];
    #pragma unroll
    for (int r = 0; r < 3; ++r)
        #pragma unroll
        for (int cc2 = 0; cc2 < 6; ++cc2)
            xr[r][cc2] = tile[h + r][w0 + cc2];

    float* oplane = out + (size_t)((b * NUMN) * CC + c) * (HH * WW) + t * 4;
    const int nstride = CC * HH * WW;   // plane stride between n

    #pragma unroll 2
    for (int n = 0; n < NUMN; ++n) {
        float nb[9];
        #pragma unroll
        for (int k = 0; k < 9; ++k) nb[k] = nlds[n * 9 + k];   // broadcast

        float acc0 = -1.0f, acc1 = -1.0f, acc2 = -1.0f, acc3 = -1.0f;
        #pragma unroll
        for (int rr = 0; rr < 3; ++rr) {        // row = rr-1
            #pragma unroll
            for (int cc2 = 0; cc2 < 3; ++cc2) { // col = cc2-1
                const float nv = nb[rr * 3 + cc2];
                // sample for out pos (h, w0+j) is tile[h+2-rr][w0+j+2-cc2]
                acc0 = fmaxf(acc0, fabsf(xr[2 - rr][0 + 2 - cc2] - nv));
                acc1 = fmaxf(acc1, fabsf(xr[2 - rr][1 + 2 - cc2] - nv));
                acc2 = fmaxf(acc2, fabsf(xr[2 - rr][2 + 2 - cc2] - nv));
                acc3 = fmaxf(acc3, fabsf(xr[2 - rr][3 + 2 - cc2] - nv));
            }
        }
        float4 v = make_float4(acc0, acc1, acc2, acc3);
        *reinterpret_cast<float4*>(oplane + (size_t)n * nstride) = v;
    }
}

extern "C" void kernel_launch(void* const* d_in, const int* in_sizes, int n_in,
                              void* d_out, int out_size, void* d_ws, size_t ws_size,
                              hipStream_t stream) {
    const float* x         = (const float*)d_in[0];
    const float* neighbors = (const float*)d_in[1];
    float* out             = (float*)d_out;

    dim3 grid(BB * CC);   // 512 blocks: one per (b, c) plane
    dim3 block(256);
    conv_nn_kernel<<<grid, block, 0, stream>>>(x, neighbors, out);
}

// Round 3
// 85.524 us; speedup vs baseline: 1.0996x; 1.0996x over previous
//
#include <hip/hip_runtime.h>

// ConvNearestNeighbor forward, MI355X (gfx950).
// x: (B=16, C=32, H=32, W=32) f32; neighbors: (NUM=32, C=32, 9) f32
// out[((b*NUM + n)*C + c)*H*W + h*W + w]
//   = max_k | x[b,c,h-row_k,w-col_k] (zero-pad) - neighbors[n,c,k] |,
//   k = 3*(row+1)+(col+1), row,col in {-1,0,1}
//
// Round 3 = round 2 with the NT-store type fixed: grid (512, 8) = 4096 blocks
// => full 32-wave/CU occupancy (round 1: 2 blocks/CU, latency-bound, 94us).
// Non-temporal ext-vector float4 stores (output 64 MiB > 32 MiB aggregate L2).

#define BB 16
#define CC 32
#define HH 32
#define WW 32
#define NUMN 32
#define NPB 4   // codebook entries per block

typedef float f32x4 __attribute__((ext_vector_type(4)));

__global__ __launch_bounds__(256) void conv_nn_kernel(
    const float* __restrict__ x,
    const float* __restrict__ neighbors,
    float* __restrict__ out)
{
    // padded x plane (halo of 1), +2 col pad for LDS bank spread
    __shared__ float tile[HH + 2][WW + 4];
    __shared__ float nlds[NPB * 9];

    const int bc = blockIdx.x;        // 0 .. B*C-1
    const int b  = bc >> 5;           // / C
    const int c  = bc & 31;           // % C
    const int n0 = blockIdx.y * NPB;  // first codebook entry for this block
    const int t  = threadIdx.x;       // 0..255

    // ---- stage x plane with zero halo (reads L2-hot: x is only 2 MiB) ----
    const float* xplane = x + (b * CC + c) * (HH * WW);
    for (int idx = t; idx < 34 * 34; idx += 256) {
        int row = idx / 34;           // 0..33
        int col = idx - row * 34;     // 0..33
        int h = row - 1, w = col - 1;
        float v = 0.0f;
        if ((unsigned)h < (unsigned)HH && (unsigned)w < (unsigned)WW)
            v = xplane[h * WW + w];
        tile[row][col] = v;
    }
    // ---- stage neighbors[n0:n0+NPB, c, :] ----
    if (t < NPB * 9) {
        int n = t / 9;
        int k = t - n * 9;
        nlds[t] = neighbors[((n0 + n) * CC + c) * 9 + k];
    }
    __syncthreads();

    // thread -> (h, w0..w0+3); plane-linear offset = h*W + w0 = 4*t
    const int h  = t >> 3;
    const int w0 = (t & 7) * 4;

    // 3 rows x 6 cols register window of the padded tile
    float xr[3][6];
    #pragma unroll
    for (int r = 0; r < 3; ++r)
        #pragma unroll
        for (int j = 0; j < 6; ++j)
            xr[r][j] = tile[h + r][w0 + j];

    float* oplane = out + (size_t)((b * NUMN + n0) * CC + c) * (HH * WW) + t * 4;
    const int nstride = CC * HH * WW;   // plane stride between consecutive n

    #pragma unroll
    for (int ni = 0; ni < NPB; ++ni) {
        float nb[9];
        #pragma unroll
        for (int k = 0; k < 9; ++k) nb[k] = nlds[ni * 9 + k];   // LDS broadcast

        // k=0 (rr=0,cc2=0) seeds the max: sample tile[h+2][w0+j+2]
        float acc0 = fabsf(xr[2][2] - nb[0]);
        float acc1 = fabsf(xr[2][3] - nb[0]);
        float acc2 = fabsf(xr[2][4] - nb[0]);
        float acc3 = fabsf(xr[2][5] - nb[0]);
        #pragma unroll
        for (int kk = 1; kk < 9; ++kk) {
            const int rr  = kk / 3;       // row+1
            const int cc2 = kk - rr * 3;  // col+1
            const float nv = nb[kk];
            acc0 = fmaxf(acc0, fabsf(xr[2 - rr][0 + 2 - cc2] - nv));
            acc1 = fmaxf(acc1, fabsf(xr[2 - rr][1 + 2 - cc2] - nv));
            acc2 = fmaxf(acc2, fabsf(xr[2 - rr][2 + 2 - cc2] - nv));
            acc3 = fmaxf(acc3, fabsf(xr[2 - rr][3 + 2 - cc2] - nv));
        }
        f32x4 v = { acc0, acc1, acc2, acc3 };
        __builtin_nontemporal_store(v,
            reinterpret_cast<f32x4*>(oplane + (size_t)ni * nstride));
    }
}

extern "C" void kernel_launch(void* const* d_in, const int* in_sizes, int n_in,
                              void* d_out, int out_size, void* d_ws, size_t ws_size,
                              hipStream_t stream) {
    const float* x         = (const float*)d_in[0];
    const float* neighbors = (const float*)d_in[1];
    float* out             = (float*)d_out;

    dim3 grid(BB * CC, NUMN / NPB);   // (512, 8) = 4096 blocks
    dim3 block(256);
    conv_nn_kernel<<<grid, block, 0, stream>>>(x, neighbors, out);
}

// Round 4
// 83.947 us; speedup vs baseline: 1.1202x; 1.0188x over previous
//
#include <hip/hip_runtime.h>

// ConvNearestNeighbor forward, MI355X (gfx950).
// x: (B=16, C=32, H=32, W=32) f32; neighbors: (NUM=32, C=32, 9) f32
// out[((b*NUM + n)*C + c)*H*W + h*W + w]
//   = max_k | x[b,c,h-row_k,w-col_k] (zero-pad) - neighbors[n,c,k] |,
//   k = 3*(row+1)+(col+1), row,col in {-1,0,1}
//
// Round 4:
//  - tile row stride 37 (was 36): 36 mod 32 == 4 collided with the
//    (lane&7)*4 col pattern -> 8-way LDS bank conflict on every xr read.
//    Stride 37 gives <=2-way (free).
//  - neighbors staged as nlds[8][12] (48B rows, 16B aligned): 9 floats
//    load as b128+b128+b32 (3 LDS instrs) instead of 9 scalar reads.
//  - grid (B*C, NUM/8) = (512,4) = 2048 blocks, 8 n per block,
//    8 blocks/CU -> full 32 waves/CU; 8 float4 NT stores per thread.

#define BB 16
#define CC 32
#define HH 32
#define WW 32
#define NUMN 32
#define NPB 8    // codebook entries per block

typedef float f32x4 __attribute__((ext_vector_type(4)));

__global__ __launch_bounds__(256, 8) void conv_nn_kernel(
    const float* __restrict__ x,
    const float* __restrict__ neighbors,
    float* __restrict__ out)
{
    __shared__ float tile[HH + 2][37];     // stride 37: <=2-way banks
    __shared__ float nlds[NPB][12];        // 48B rows, 16B aligned

    const int bc = blockIdx.x;        // 0 .. B*C-1
    const int b  = bc >> 5;           // / C
    const int c  = bc & 31;           // % C
    const int n0 = blockIdx.y * NPB;  // first codebook entry for this block
    const int t  = threadIdx.x;       // 0..255

    // ---- stage x plane with zero halo (L2-hot: x is only 2 MiB) ----
    const float* xplane = x + (b * CC + c) * (HH * WW);
    for (int idx = t; idx < 34 * 34; idx += 256) {
        int row = idx / 34;           // 0..33
        int col = idx - row * 34;     // 0..33
        int h = row - 1, w = col - 1;
        float v = 0.0f;
        if ((unsigned)h < (unsigned)HH && (unsigned)w < (unsigned)WW)
            v = xplane[h * WW + w];
        tile[row][col] = v;
    }
    // ---- stage neighbors[n0:n0+NPB, c, :] into [n][12] layout ----
    if (t < NPB * 9) {
        int n = t / 9;
        int k = t - n * 9;
        nlds[n][k] = neighbors[((n0 + n) * CC + c) * 9 + k];
    }
    __syncthreads();

    // thread -> (h, w0..w0+3); plane-linear offset = h*W + w0 = 4*t
    const int h  = t >> 3;
    const int w0 = (t & 7) * 4;

    // 3 rows x 6 cols register window of the padded tile
    float xr[3][6];
    #pragma unroll
    for (int r = 0; r < 3; ++r)
        #pragma unroll
        for (int j = 0; j < 6; ++j)
            xr[r][j] = tile[h + r][w0 + j];

    float* oplane = out + (size_t)((b * NUMN + n0) * CC + c) * (HH * WW) + t * 4;
    const int nstride = CC * HH * WW;   // plane stride between consecutive n

    #pragma unroll
    for (int ni = 0; ni < NPB; ++ni) {
        // 9 neighbor taps: vectorized LDS reads (b128 + b128 + b32)
        f32x4 nlo = *reinterpret_cast<const f32x4*>(&nlds[ni][0]);
        f32x4 nhi = *reinterpret_cast<const f32x4*>(&nlds[ni][4]);
        float nb[9] = { nlo.x, nlo.y, nlo.z, nlo.w,
                        nhi.x, nhi.y, nhi.z, nhi.w, nlds[ni][8] };

        // k=0 (rr=0,cc2=0) seeds the max: sample xr[2][j+2]
        float acc0 = fabsf(xr[2][2] - nb[0]);
        float acc1 = fabsf(xr[2][3] - nb[0]);
        float acc2 = fabsf(xr[2][4] - nb[0]);
        float acc3 = fabsf(xr[2][5] - nb[0]);
        #pragma unroll
        for (int kk = 1; kk < 9; ++kk) {
            const int rr  = kk / 3;       // row+1
            const int cc2 = kk - rr * 3;  // col+1
            const float nv = nb[kk];
            acc0 = fmaxf(acc0, fabsf(xr[2 - rr][0 + 2 - cc2] - nv));
            acc1 = fmaxf(acc1, fabsf(xr[2 - rr][1 + 2 - cc2] - nv));
            acc2 = fmaxf(acc2, fabsf(xr[2 - rr][2 + 2 - cc2] - nv));
            acc3 = fmaxf(acc3, fabsf(xr[2 - rr][3 + 2 - cc2] - nv));
        }
        f32x4 v = { acc0, acc1, acc2, acc3 };
        __builtin_nontemporal_store(v,
            reinterpret_cast<f32x4*>(oplane + (size_t)ni * nstride));
    }
}

extern "C" void kernel_launch(void* const* d_in, const int* in_sizes, int n_in,
                              void* d_out, int out_size, void* d_ws, size_t ws_size,
                              hipStream_t stream) {
    const float* x         = (const float*)d_in[0];
    const float* neighbors = (const float*)d_in[1];
    float* out             = (float*)d_out;

    dim3 grid(BB * CC, NUMN / NPB);   // (512, 4) = 2048 blocks
    dim3 block(256);
    conv_nn_kernel<<<grid, block, 0, stream>>>(x, neighbors, out);
}